// Round 5
// baseline (868.597 us; speedup 1.0000x reference)
//
#include <hip/hip_runtime.h>

#define N_NODES 10000
#define N_PAD 10016
#define N_EDGES 160000
#define IN_CH 128
#define H 64
#define H2 128
#define OUT_CH 112
#define NLAYERS 28

// ---------------- CSR build ----------------
__global__ __launch_bounds__(256) void k_count(const int* __restrict__ ei, int* __restrict__ deg) {
  int e = blockIdx.x * 256 + threadIdx.x;
  atomicAdd(&deg[ei[N_EDGES + e]], 1);   // E = 625*256 exactly
}

__global__ __launch_bounds__(1024) void k_scan(const int* __restrict__ deg, int* __restrict__ offs) {
  __shared__ int sums[1024];
  constexpr int CH = 10;
  int t = threadIdx.x;
  int base = t * CH;
  int local[CH];
  int s = 0;
  #pragma unroll
  for (int i = 0; i < CH; i++) {
    int idx = base + i;
    int v = (idx < N_NODES) ? deg[idx] : 0;
    local[i] = s; s += v;
  }
  sums[t] = s;
  __syncthreads();
  for (int off = 1; off < 1024; off <<= 1) {
    int v = (t >= off) ? sums[t - off] : 0;
    __syncthreads();
    sums[t] += v;
    __syncthreads();
  }
  int prev = (t == 0) ? 0 : sums[t - 1];
  #pragma unroll
  for (int i = 0; i < CH; i++) {
    int idx = base + i;
    if (idx < N_NODES) offs[idx] = prev + local[i];
  }
  if (t == 1023) offs[N_NODES] = sums[1023];
}

__global__ __launch_bounds__(256) void k_fill(const int* __restrict__ ei, const int* __restrict__ offs,
                                              int* __restrict__ cur, int* __restrict__ csr) {
  int e = blockIdx.x * 256 + threadIdx.x;
  int d = ei[N_EDGES + e];
  int p = offs[d] + atomicAdd(&cur[d], 1);
  csr[p] = ei[e];
}

// ---------------- weight packing (plain, coalesced-per-lane) ----------------
// W1P[l][(g*64+lane)*8 + kk*2 + c] = W1[l][(4g+kk)*128 + lane*2 + c]  (g<16)
// W2P[l][(g*64+lane)*4 + j]        = W2[l][(4g+j)*64 + lane]          (g<32)
__global__ __launch_bounds__(256) void k_pack(const float* __restrict__ W1, const float* __restrict__ W2,
                                              float* __restrict__ W1P, float* __restrict__ W2P) {
  int l = blockIdx.x;
  const float* w1 = W1 + l * 8192; float* p1 = W1P + l * 8192;
  const float* w2 = W2 + l * 8192; float* p2 = W2P + l * 8192;
  int t = threadIdx.x;
  for (int i = t; i < 8192; i += 256) {
    int g = i >> 9, r = i & 511;
    int lane = r >> 3, j = r & 7, kk = j >> 1, c = j & 1;
    p1[i] = w1[(4 * g + kk) * H2 + lane * 2 + c];
  }
  for (int i = t; i < 8192; i += 256) {
    int g = i >> 8, r = i & 255;
    int lane = r >> 2, j = r & 3;
    p2[i] = w2[(4 * g + j) * H + lane];
  }
}

// ---------------- encoder: h = x@W+b ; z0 = relu(LN(h; g0,b0)) ----------------
__global__ __launch_bounds__(256) void k_encoder(
    const float* __restrict__ x, const float* __restrict__ Wenc, const float* __restrict__ benc,
    const float* __restrict__ lng, const float* __restrict__ lnb,
    float* __restrict__ h, float* __restrict__ z) {
  __shared__ float Xs[8][IN_CH];
  int t = threadIdx.x;
  int tile = blockIdx.x * 8;
  {
    int r = t >> 5, c4 = t & 31;
    float4 v = ((const float4*)x)[(tile + r) * 32 + c4];
    *(float4*)&Xs[r][c4 * 4] = v;
  }
  __syncthreads();
  int lane = t & 63;
  int wave = __builtin_amdgcn_readfirstlane(t >> 6);
  int n0 = wave * 2;
  float b = benc[lane];
  float a0 = b, a1 = b;
  #pragma unroll
  for (int k = 0; k < IN_CH; k += 4) {
    float4 X0 = *(float4*)&Xs[n0][k];
    float4 X1 = *(float4*)&Xs[n0 + 1][k];
    float w0 = Wenc[(k + 0) * H + lane];
    float w1 = Wenc[(k + 1) * H + lane];
    float w2 = Wenc[(k + 2) * H + lane];
    float w3 = Wenc[(k + 3) * H + lane];
    a0 = fmaf(X0.x, w0, a0); a0 = fmaf(X0.y, w1, a0); a0 = fmaf(X0.z, w2, a0); a0 = fmaf(X0.w, w3, a0);
    a1 = fmaf(X1.x, w0, a1); a1 = fmaf(X1.y, w1, a1); a1 = fmaf(X1.z, w2, a1); a1 = fmaf(X1.w, w3, a1);
  }
  float g = lng[lane], bb = lnb[lane];
  #pragma unroll
  for (int i = 0; i < 2; i++) {
    float a = (i == 0) ? a0 : a1;
    float s = a, q = a * a;
    #pragma unroll
    for (int m = 1; m < 64; m <<= 1) { s += __shfl_xor(s, m); q += __shfl_xor(q, m); }
    float mu = s * (1.0f / 64.0f);
    float var = q * (1.0f / 64.0f) - mu * mu;
    float rs = rsqrtf(var + 1e-5f);
    int gn = tile + n0 + i;
    h[gn * H + lane] = a;
    z[gn * H + lane] = fmaxf(fmaf((a - mu) * rs, g, bb), 0.f);
  }
}

// ---------------- phase A: softmax aggregation (1 node / wave, 16-wide rounds) ----------------
__global__ __launch_bounds__(256) void k_agg(
    const float* __restrict__ zc, const int* __restrict__ offs, const int* __restrict__ csr,
    const float* __restrict__ tvec, float* __restrict__ As, int l) {
  int t = threadIdx.x;
  int lane = t & 63;
  int gn = blockIdx.x * 4 + (t >> 6);
  float tl = tvec[l] * 1.44269504088896340736f;
  int e0 = offs[gn], e1 = offs[gn + 1];
  float den = 0.f, acc = 0.f;
  for (int base = e0; base < e1; base += 16) {
    // 16 independent csr loads (clamped), then 16 independent row-gathers.
    int idx[16];
    #pragma unroll
    for (int j = 0; j < 16; j++) {
      int ee = base + j;
      idx[j] = csr[ee < e1 ? ee : e1 - 1];
    }
    float vv[16];
    #pragma unroll
    for (int j = 0; j < 16; j++)
      vv[j] = zc[idx[j] * H + lane];
    #pragma unroll
    for (int j = 0; j < 16; j++) {
      float v = vv[j] + 1e-7f;
      float p = ((base + j) < e1) ? exp2f(v * tl) : 0.f;
      den += p;
      acc = fmaf(p, v, acc);
    }
  }
  As[gn * H + lane] = acc / (den + 1e-16f) + zc[gn * H + lane];
}

// ---------------- phase B/C/D: MLP + residual + next-layer pre-norm ----------------
// 250 blocks x 4 waves x 10 nodes/wave = 10000 exactly; 1 block/CU, no stragglers.
__global__ __launch_bounds__(256) void k_mlp(
    const float* __restrict__ As_g, float* __restrict__ zn, float* __restrict__ h,
    const float* __restrict__ W1P, const float* __restrict__ b1,
    const float* __restrict__ mg, const float* __restrict__ mb,
    const float* __restrict__ W2P, const float* __restrict__ b2,
    const float* __restrict__ lngn, const float* __restrict__ lnbn,
    int l, int last) {
  __shared__ float Asl[40][H];     // 10 KB
  __shared__ float Us[40][H2];     // 20 KB
  int t = threadIdx.x;
  int lane = t & 63;
  int wave = __builtin_amdgcn_readfirstlane(t >> 6);
  int tile = blockIdx.x * 40;

  for (int idx = t; idx < 640; idx += 256) {
    int r = idx >> 4, c = (idx & 15) * 4;
    *(float4*)&Asl[r][c] = *(const float4*)&As_g[(tile + r) * H + c];
  }
  __syncthreads();

  int n0 = wave * 10;
  // ---- phase B: u1 = A @ W1 + b1 ; Us = relu(LN(u1))
  {
    const float* W1Pl = W1P + (size_t)l * 8192;
    const float* b1l = b1 + l * H2;
    int c0 = lane * 2;
    float bb0 = b1l[c0], bb1 = b1l[c0 + 1];
    float u0[10], u1[10];
    #pragma unroll
    for (int i = 0; i < 10; i++) { u0[i] = bb0; u1[i] = bb1; }
    #pragma unroll
    for (int g = 0; g < 16; g++) {
      float4 wa = *(const float4*)&W1Pl[(g * 64 + lane) * 8];
      float4 wb = *(const float4*)&W1Pl[(g * 64 + lane) * 8 + 4];
      #pragma unroll
      for (int i = 0; i < 10; i++) {
        float4 A = *(float4*)&Asl[n0 + i][g * 4];
        u0[i] = fmaf(A.x, wa.x, u0[i]); u1[i] = fmaf(A.x, wa.y, u1[i]);
        u0[i] = fmaf(A.y, wa.z, u0[i]); u1[i] = fmaf(A.y, wa.w, u1[i]);
        u0[i] = fmaf(A.z, wb.x, u0[i]); u1[i] = fmaf(A.z, wb.y, u1[i]);
        u0[i] = fmaf(A.w, wb.z, u0[i]); u1[i] = fmaf(A.w, wb.w, u1[i]);
      }
    }
    float s[10], q[10];
    #pragma unroll
    for (int i = 0; i < 10; i++) { s[i] = u0[i] + u1[i]; q[i] = u0[i] * u0[i] + u1[i] * u1[i]; }
    #pragma unroll
    for (int m = 1; m < 64; m <<= 1) {
      #pragma unroll
      for (int i = 0; i < 10; i++) { s[i] += __shfl_xor(s[i], m); q[i] += __shfl_xor(q[i], m); }
    }
    const float* mgl = mg + l * H2;
    const float* mbl = mb + l * H2;
    float g0 = mgl[c0], g1 = mgl[c0 + 1], hb0 = mbl[c0], hb1 = mbl[c0 + 1];
    #pragma unroll
    for (int i = 0; i < 10; i++) {
      float mu = s[i] * (1.0f / 128.0f);
      float rs = rsqrtf(q[i] * (1.0f / 128.0f) - mu * mu + 1e-5f);
      float o0 = fmaxf(fmaf((u0[i] - mu) * rs, g0, hb0), 0.f);
      float o1 = fmaxf(fmaf((u1[i] - mu) * rs, g1, hb1), 0.f);
      *(float2*)&Us[n0 + i][c0] = make_float2(o0, o1);
    }
  }
  // no barrier: phase C reads only this wave's Us rows

  // ---- phase C: u2 = Us @ W2 + b2 ; h += u2 ; phase D: z_next = relu(LN(h))
  {
    const float* W2Pl = W2P + (size_t)l * 8192;
    const float* b2l = b2 + l * H;
    float bb = b2l[lane];
    float v[10];
    #pragma unroll
    for (int i = 0; i < 10; i++) v[i] = bb;
    #pragma unroll
    for (int g = 0; g < 32; g++) {
      float4 w = *(const float4*)&W2Pl[(g * 64 + lane) * 4];
      #pragma unroll
      for (int i = 0; i < 10; i++) {
        float4 X = *(float4*)&Us[n0 + i][g * 4];
        v[i] = fmaf(X.x, w.x, v[i]); v[i] = fmaf(X.y, w.y, v[i]);
        v[i] = fmaf(X.z, w.z, v[i]); v[i] = fmaf(X.w, w.w, v[i]);
      }
    }
    float hv[10], s[10], q[10];
    #pragma unroll
    for (int i = 0; i < 10; i++) {
      int gn = tile + n0 + i;
      hv[i] = h[gn * H + lane] + v[i];
      h[gn * H + lane] = hv[i];
      s[i] = hv[i]; q[i] = hv[i] * hv[i];
    }
    if (!last) {
      #pragma unroll
      for (int m = 1; m < 64; m <<= 1) {
        #pragma unroll
        for (int i = 0; i < 10; i++) { s[i] += __shfl_xor(s[i], m); q[i] += __shfl_xor(q[i], m); }
      }
      float gg = lngn[lane], gb = lnbn[lane];
      #pragma unroll
      for (int i = 0; i < 10; i++) {
        float mu = s[i] * (1.0f / 64.0f);
        float rs = rsqrtf(q[i] * (1.0f / 64.0f) - mu * mu + 1e-5f);
        zn[(tile + n0 + i) * H + lane] = fmaxf(fmaf((hv[i] - mu) * rs, gg, gb), 0.f);
      }
    }
  }
}

// ---------------- head: out = h @ Wh + bh ----------------
__global__ __launch_bounds__(256) void k_head(const float* __restrict__ h, const float* __restrict__ Wh,
                                              const float* __restrict__ bh, float* __restrict__ out) {
  __shared__ float Hs[8][H];
  int t = threadIdx.x;
  int tile = blockIdx.x * 8;
  if (t < 128) {
    int r = t >> 4, c4 = t & 15;
    float4 v = ((const float4*)h)[(tile + r) * 16 + c4];
    *(float4*)&Hs[r][c4 * 4] = v;
  }
  __syncthreads();
  int lane = t & 63;
  int wave = __builtin_amdgcn_readfirstlane(t >> 6);
  int n0 = wave * 2;
  int c2 = 64 + ((lane < 48) ? lane : 47);
  float b0 = bh[lane], b1 = bh[c2];
  float a00 = b0, a01 = b1, a10 = b0, a11 = b1;
  #pragma unroll
  for (int k = 0; k < H; k += 4) {
    float4 X0 = *(float4*)&Hs[n0][k];
    float4 X1 = *(float4*)&Hs[n0 + 1][k];
    float wA0 = Wh[(k + 0) * OUT_CH + lane], wB0 = Wh[(k + 0) * OUT_CH + c2];
    float wA1 = Wh[(k + 1) * OUT_CH + lane], wB1 = Wh[(k + 1) * OUT_CH + c2];
    float wA2 = Wh[(k + 2) * OUT_CH + lane], wB2 = Wh[(k + 2) * OUT_CH + c2];
    float wA3 = Wh[(k + 3) * OUT_CH + lane], wB3 = Wh[(k + 3) * OUT_CH + c2];
    a00 = fmaf(X0.x, wA0, a00); a01 = fmaf(X0.x, wB0, a01);
    a00 = fmaf(X0.y, wA1, a00); a01 = fmaf(X0.y, wB1, a01);
    a00 = fmaf(X0.z, wA2, a00); a01 = fmaf(X0.z, wB2, a01);
    a00 = fmaf(X0.w, wA3, a00); a01 = fmaf(X0.w, wB3, a01);
    a10 = fmaf(X1.x, wA0, a10); a11 = fmaf(X1.x, wB0, a11);
    a10 = fmaf(X1.y, wA1, a10); a11 = fmaf(X1.y, wB1, a11);
    a10 = fmaf(X1.z, wA2, a10); a11 = fmaf(X1.z, wB2, a11);
    a10 = fmaf(X1.w, wA3, a10); a11 = fmaf(X1.w, wB3, a11);
  }
  int gn0 = tile + n0;
  out[gn0 * OUT_CH + lane] = a00;
  out[(gn0 + 1) * OUT_CH + lane] = a10;
  if (lane < 48) {
    out[gn0 * OUT_CH + 64 + lane] = a01;
    out[(gn0 + 1) * OUT_CH + 64 + lane] = a11;
  }
}

extern "C" void kernel_launch(void* const* d_in, const int* in_sizes, int n_in,
                              void* d_out, int out_size, void* d_ws, size_t ws_size,
                              hipStream_t stream) {
  (void)in_sizes; (void)n_in; (void)out_size; (void)ws_size;
  const float* x    = (const float*)d_in[0];
  const int*   ei   = (const int*)d_in[1];
  const float* encW = (const float*)d_in[2];
  const float* encb = (const float*)d_in[3];
  const float* lng  = (const float*)d_in[4];
  const float* lnb  = (const float*)d_in[5];
  const float* tv   = (const float*)d_in[6];
  const float* W1   = (const float*)d_in[7];
  const float* b1   = (const float*)d_in[8];
  const float* mg   = (const float*)d_in[9];
  const float* mb   = (const float*)d_in[10];
  const float* W2   = (const float*)d_in[11];
  const float* b2   = (const float*)d_in[12];
  const float* Wh   = (const float*)d_in[13];
  const float* bh   = (const float*)d_in[14];

  char* ws = (char*)d_ws;
  int*   deg  = (int*)(ws + 0);            // N ints
  int*   cur  = (int*)(ws + 40000);        // N ints
  int*   offs = (int*)(ws + 80000);        // N+1 ints
  int*   csr  = (int*)(ws + 120064);       // E ints
  float* h    = (float*)(ws + 760064);     // N_PAD*64
  float* z0   = (float*)(ws + 3324160);    // N_PAD*64
  float* z1   = (float*)(ws + 5888256);    // N_PAD*64
  float* As   = (float*)(ws + 8452352);    // N_PAD*64
  float* W1P  = (float*)(ws + 11016448);   // 28*8192
  float* W2P  = (float*)(ws + 11933952);   // 28*8192 (end 12,851,456)

  hipMemsetAsync(ws, 0, 80000, stream);    // deg + cur
  k_count<<<625, 256, 0, stream>>>(ei, deg);
  k_pack<<<28, 256, 0, stream>>>(W1, W2, W1P, W2P);
  k_scan<<<1, 1024, 0, stream>>>(deg, offs);
  k_fill<<<625, 256, 0, stream>>>(ei, offs, cur, csr);
  k_encoder<<<1250, 256, 0, stream>>>(x, encW, encb, lng, lnb, h, z0);

  float* zc = z0;
  float* znx = z1;
  for (int l = 0; l < NLAYERS; l++) {
    int ln_next = (l + 1 < NLAYERS) ? (l + 1) : l;
    k_agg<<<2500, 256, 0, stream>>>(zc, offs, csr, tv, As, l);
    k_mlp<<<250, 256, 0, stream>>>(As, znx, h, W1P, b1, mg, mb, W2P, b2,
                                   lng + ln_next * H, lnb + ln_next * H,
                                   l, (l == NLAYERS - 1) ? 1 : 0);
    float* tmp = zc; zc = znx; znx = tmp;
  }
  k_head<<<1250, 256, 0, stream>>>(h, Wh, bh, (float*)d_out);
}

// Round 6
// 703.552 us; speedup vs baseline: 1.2346x; 1.2346x over previous
//
#include <hip/hip_runtime.h>

#define N_NODES 10000
#define N_PAD 10016
#define N_EDGES 160000
#define IN_CH 128
#define H 64
#define H2 128
#define OUT_CH 112
#define NLAYERS 28
#define LOG2E 1.44269504088896340736f

// global_load_lds: async global->LDS, 16B per lane, LDS dest = uniform base + lane*16
#define GLDS16(gp, lp) __builtin_amdgcn_global_load_lds( \
    (const __attribute__((address_space(1))) void*)(gp),  \
    (__attribute__((address_space(3))) void*)(lp), 16, 0, 0)

// ---------------- CSR build ----------------
__global__ __launch_bounds__(256) void k_count(const int* __restrict__ ei, int* __restrict__ deg) {
  int e = blockIdx.x * 256 + threadIdx.x;
  atomicAdd(&deg[ei[N_EDGES + e]], 1);   // E = 625*256 exactly
}

__global__ __launch_bounds__(1024) void k_scan(const int* __restrict__ deg, int* __restrict__ offs) {
  __shared__ int sums[1024];
  constexpr int CH = 10;
  int t = threadIdx.x;
  int base = t * CH;
  int local[CH];
  int s = 0;
  #pragma unroll
  for (int i = 0; i < CH; i++) {
    int idx = base + i;
    int v = (idx < N_NODES) ? deg[idx] : 0;
    local[i] = s; s += v;
  }
  sums[t] = s;
  __syncthreads();
  for (int off = 1; off < 1024; off <<= 1) {
    int v = (t >= off) ? sums[t - off] : 0;
    __syncthreads();
    sums[t] += v;
    __syncthreads();
  }
  int prev = (t == 0) ? 0 : sums[t - 1];
  #pragma unroll
  for (int i = 0; i < CH; i++) {
    int idx = base + i;
    if (idx < N_NODES) offs[idx] = prev + local[i];
  }
  if (t == 1023) offs[N_NODES] = sums[1023];
}

__global__ __launch_bounds__(256) void k_fill(const int* __restrict__ ei, const int* __restrict__ offs,
                                              int* __restrict__ cur, int* __restrict__ csr) {
  int e = blockIdx.x * 256 + threadIdx.x;
  int d = ei[N_EDGES + e];
  int p = offs[d] + atomicAdd(&cur[d], 1);
  csr[p] = ei[e];
}

// ---------------- weight packing ----------------
// WP[l] = 16384 floats. W1 region [0,8192): 2048 16B-slots, slot q holds
// (g,lane,h) = decode(q ^ ((q>>3)&1)) with qu = g*128+lane*2+h; element e:
// j=h*4+e, kk=j>>1, c=j&1 -> W1[(4g+kk)*128 + lane*2+c].  (XOR = bank de-conflict)
// W2 region [8192,16384): idx 8192+(g*64+lane)*4+j = W2[(4g+j)*64+lane].
__global__ __launch_bounds__(256) void k_pack(const float* __restrict__ W1, const float* __restrict__ W2,
                                              float* __restrict__ WP) {
  int l = blockIdx.x;
  const float* w1 = W1 + l * 8192;
  const float* w2 = W2 + l * 8192;
  float* p = WP + (size_t)l * 16384;
  int t = threadIdx.x;
  for (int i = t; i < 8192; i += 256) {
    int q = i >> 2, e = i & 3;
    int qu = q ^ ((q >> 3) & 1);
    int g = qu >> 7, lane = (qu >> 1) & 63, hh = qu & 1;
    int j = hh * 4 + e, kk = j >> 1, c = j & 1;
    p[i] = w1[(4 * g + kk) * H2 + lane * 2 + c];
  }
  for (int i = t; i < 8192; i += 256) {
    int g = i >> 8, r = i & 255;
    int lane = r >> 2, j = r & 3;
    p[8192 + i] = w2[(4 * g + j) * H + lane];
  }
}

// ---------------- encoder: h = x@W+b ; z0 = relu(LN(h; g0,b0)) ----------------
__global__ __launch_bounds__(256) void k_encoder(
    const float* __restrict__ x, const float* __restrict__ Wenc, const float* __restrict__ benc,
    const float* __restrict__ lng, const float* __restrict__ lnb,
    float* __restrict__ h, float* __restrict__ z) {
  __shared__ float Xs[8][IN_CH];
  int t = threadIdx.x;
  int tile = blockIdx.x * 8;
  {
    int r = t >> 5, c4 = t & 31;
    float4 v = ((const float4*)x)[(tile + r) * 32 + c4];
    *(float4*)&Xs[r][c4 * 4] = v;
  }
  __syncthreads();
  int lane = t & 63;
  int wave = __builtin_amdgcn_readfirstlane(t >> 6);
  int n0 = wave * 2;
  float b = benc[lane];
  float a0 = b, a1 = b;
  #pragma unroll
  for (int k = 0; k < IN_CH; k += 4) {
    float4 X0 = *(float4*)&Xs[n0][k];
    float4 X1 = *(float4*)&Xs[n0 + 1][k];
    float w0 = Wenc[(k + 0) * H + lane];
    float w1 = Wenc[(k + 1) * H + lane];
    float w2 = Wenc[(k + 2) * H + lane];
    float w3 = Wenc[(k + 3) * H + lane];
    a0 = fmaf(X0.x, w0, a0); a0 = fmaf(X0.y, w1, a0); a0 = fmaf(X0.z, w2, a0); a0 = fmaf(X0.w, w3, a0);
    a1 = fmaf(X1.x, w0, a1); a1 = fmaf(X1.y, w1, a1); a1 = fmaf(X1.z, w2, a1); a1 = fmaf(X1.w, w3, a1);
  }
  float g = lng[lane], bb = lnb[lane];
  #pragma unroll
  for (int i = 0; i < 2; i++) {
    float a = (i == 0) ? a0 : a1;
    float s = a, q = a * a;
    #pragma unroll
    for (int m = 1; m < 64; m <<= 1) { s += __shfl_xor(s, m); q += __shfl_xor(q, m); }
    float mu = s * (1.0f / 64.0f);
    float var = q * (1.0f / 64.0f) - mu * mu;
    float rs = rsqrtf(var + 1e-5f);
    int gn = tile + n0 + i;
    h[gn * H + lane] = a;
    z[gn * H + lane] = fmaxf(fmaf((a - mu) * rs, g, bb), 0.f);
  }
}

// ---------------- fused GENConv layer: agg + MLP + residual + next pre-norm ----------------
// 500 blocks x 4 waves x 5 nodes/wave = 10000. Weights async-staged into LDS under agg.
__global__ __launch_bounds__(256, 2) void k_layer(
    const float* __restrict__ zc, float* __restrict__ zn, float* __restrict__ h,
    const int* __restrict__ offs, const int* __restrict__ csr,
    const float* __restrict__ tvec, const float* __restrict__ WP,
    const float* __restrict__ b1,
    const float* __restrict__ mg, const float* __restrict__ mb,
    const float* __restrict__ b2,
    const float* __restrict__ lngn, const float* __restrict__ lnbn,
    int l, int last) {
  __shared__ float Ws[16384];      // 64 KB packed W1|W2
  __shared__ float Asl[20][H];     // 5 KB
  __shared__ float Us[20][H2];     // 10 KB
  int t = threadIdx.x;
  int lane = t & 63;
  int wave = __builtin_amdgcn_readfirstlane(t >> 6);
  int tile = blockIdx.x * 20;
  int nb0 = tile + wave * 5;

  // ---- issue async weight stage (hides under agg) ----
  const float* WPl = WP + (size_t)l * 16384;
  #pragma unroll
  for (int i = 0; i < 16; i++) {
    int off = (i * 256 + t) * 4;
    GLDS16(WPl + off, Ws + off);
  }

  // ---- phase A: softmax aggregation, 5 nodes/wave, first rounds interleaved ----
  float tl = tvec[l] * LOG2E;
  int e0[5], e1[5];
  #pragma unroll
  for (int i = 0; i < 5; i++) { e0[i] = offs[nb0 + i]; e1[i] = offs[nb0 + i + 1]; }
  float den[5], acc[5];
  {
    int idx[5][16];
    #pragma unroll
    for (int i = 0; i < 5; i++) {
      #pragma unroll
      for (int j = 0; j < 16; j++) {
        int ee = e0[i] + j;
        int ce = ee < e1[i] ? ee : e1[i] - 1;
        idx[i][j] = csr[ce < 0 ? 0 : ce];
      }
    }
    float vv[5][16];
    #pragma unroll
    for (int i = 0; i < 5; i++)
      #pragma unroll
      for (int j = 0; j < 16; j++)
        vv[i][j] = zc[idx[i][j] * H + lane];
    #pragma unroll
    for (int i = 0; i < 5; i++) {
      den[i] = 0.f; acc[i] = 0.f;
      #pragma unroll
      for (int j = 0; j < 16; j++) {
        float v = vv[i][j] + 1e-7f;
        float pz = (e0[i] + j < e1[i]) ? exp2f(v * tl) : 0.f;
        den[i] += pz;
        acc[i] = fmaf(pz, v, acc[i]);
      }
    }
  }
  // tail rounds (deg > 16)
  #pragma unroll
  for (int i = 0; i < 5; i++) {
    for (int base = e0[i] + 16; base < e1[i]; base += 16) {
      int id2[16]; float v2[16];
      #pragma unroll
      for (int j = 0; j < 16; j++) {
        int ee = base + j;
        id2[j] = csr[ee < e1[i] ? ee : e1[i] - 1];
      }
      #pragma unroll
      for (int j = 0; j < 16; j++)
        v2[j] = zc[id2[j] * H + lane];
      #pragma unroll
      for (int j = 0; j < 16; j++) {
        float v = v2[j] + 1e-7f;
        float pz = (base + j < e1[i]) ? exp2f(v * tl) : 0.f;
        den[i] += pz;
        acc[i] = fmaf(pz, v, acc[i]);
      }
    }
  }
  #pragma unroll
  for (int i = 0; i < 5; i++)
    Asl[wave * 5 + i][lane] = acc[i] / (den[i] + 1e-16f) + zc[(nb0 + i) * H + lane];

  __syncthreads();   // drains vmcnt(0): weights now in LDS; Asl visible

  int n0 = wave * 5;
  // ---- phase B: u1 = A @ W1 + b1 ; Us = relu(LN(u1)) ----
  {
    const float* b1l = b1 + l * H2;
    int c0 = lane * 2;
    float bb0 = b1l[c0], bb1 = b1l[c0 + 1];
    float u0[5], u1[5];
    #pragma unroll
    for (int i = 0; i < 5; i++) { u0[i] = bb0; u1[i] = bb1; }
    int bsw = (lane >> 2) & 1;   // swizzle bit
    #pragma unroll
    for (int g = 0; g < 16; g++) {
      float4 wa = *(float4*)&Ws[(g * 128 + lane * 2 + bsw) * 4];
      float4 wb = *(float4*)&Ws[(g * 128 + lane * 2 + 1 - bsw) * 4];
      #pragma unroll
      for (int i = 0; i < 5; i++) {
        float4 A = *(float4*)&Asl[n0 + i][g * 4];
        u0[i] = fmaf(A.x, wa.x, u0[i]); u1[i] = fmaf(A.x, wa.y, u1[i]);
        u0[i] = fmaf(A.y, wa.z, u0[i]); u1[i] = fmaf(A.y, wa.w, u1[i]);
        u0[i] = fmaf(A.z, wb.x, u0[i]); u1[i] = fmaf(A.z, wb.y, u1[i]);
        u0[i] = fmaf(A.w, wb.z, u0[i]); u1[i] = fmaf(A.w, wb.w, u1[i]);
      }
    }
    float s[5], q[5];
    #pragma unroll
    for (int i = 0; i < 5; i++) { s[i] = u0[i] + u1[i]; q[i] = u0[i] * u0[i] + u1[i] * u1[i]; }
    #pragma unroll
    for (int m = 1; m < 64; m <<= 1) {
      #pragma unroll
      for (int i = 0; i < 5; i++) { s[i] += __shfl_xor(s[i], m); q[i] += __shfl_xor(q[i], m); }
    }
    const float* mgl = mg + l * H2;
    const float* mbl = mb + l * H2;
    float g0 = mgl[c0], g1 = mgl[c0 + 1], hb0 = mbl[c0], hb1 = mbl[c0 + 1];
    #pragma unroll
    for (int i = 0; i < 5; i++) {
      float mu = s[i] * (1.0f / 128.0f);
      float rs = rsqrtf(q[i] * (1.0f / 128.0f) - mu * mu + 1e-5f);
      float o0 = fmaxf(fmaf((u0[i] - mu) * rs, g0, hb0), 0.f);
      float o1 = fmaxf(fmaf((u1[i] - mu) * rs, g1, hb1), 0.f);
      *(float2*)&Us[n0 + i][c0] = make_float2(o0, o1);
    }
  }
  // no barrier: phase C reads only own-wave Us rows

  // ---- phase C: u2 = Us @ W2 + b2 ; h += u2 ; phase D: z_next = relu(LN(h)) ----
  {
    const float* b2l = b2 + l * H;
    float bb = b2l[lane];
    float v[5];
    #pragma unroll
    for (int i = 0; i < 5; i++) v[i] = bb;
    #pragma unroll
    for (int g = 0; g < 32; g++) {
      float4 w = *(float4*)&Ws[8192 + (g * 64 + lane) * 4];
      #pragma unroll
      for (int i = 0; i < 5; i++) {
        float4 X = *(float4*)&Us[n0 + i][g * 4];
        v[i] = fmaf(X.x, w.x, v[i]); v[i] = fmaf(X.y, w.y, v[i]);
        v[i] = fmaf(X.z, w.z, v[i]); v[i] = fmaf(X.w, w.w, v[i]);
      }
    }
    float hv[5], s[5], q[5];
    #pragma unroll
    for (int i = 0; i < 5; i++) {
      int gn = nb0 + i;
      hv[i] = h[gn * H + lane] + v[i];
      h[gn * H + lane] = hv[i];
      s[i] = hv[i]; q[i] = hv[i] * hv[i];
    }
    if (!last) {
      #pragma unroll
      for (int m = 1; m < 64; m <<= 1) {
        #pragma unroll
        for (int i = 0; i < 5; i++) { s[i] += __shfl_xor(s[i], m); q[i] += __shfl_xor(q[i], m); }
      }
      float gg = lngn[lane], gb = lnbn[lane];
      #pragma unroll
      for (int i = 0; i < 5; i++) {
        float mu = s[i] * (1.0f / 64.0f);
        float rs = rsqrtf(q[i] * (1.0f / 64.0f) - mu * mu + 1e-5f);
        zn[(nb0 + i) * H + lane] = fmaxf(fmaf((hv[i] - mu) * rs, gg, gb), 0.f);
      }
    }
  }
}

// ---------------- head: out = h @ Wh + bh ----------------
__global__ __launch_bounds__(256) void k_head(const float* __restrict__ h, const float* __restrict__ Wh,
                                              const float* __restrict__ bh, float* __restrict__ out) {
  __shared__ float Hs[8][H];
  int t = threadIdx.x;
  int tile = blockIdx.x * 8;
  if (t < 128) {
    int r = t >> 4, c4 = t & 15;
    float4 v = ((const float4*)h)[(tile + r) * 16 + c4];
    *(float4*)&Hs[r][c4 * 4] = v;
  }
  __syncthreads();
  int lane = t & 63;
  int wave = __builtin_amdgcn_readfirstlane(t >> 6);
  int n0 = wave * 2;
  int c2 = 64 + ((lane < 48) ? lane : 47);
  float b0 = bh[lane], b1 = bh[c2];
  float a00 = b0, a01 = b1, a10 = b0, a11 = b1;
  #pragma unroll
  for (int k = 0; k < H; k += 4) {
    float4 X0 = *(float4*)&Hs[n0][k];
    float4 X1 = *(float4*)&Hs[n0 + 1][k];
    float wA0 = Wh[(k + 0) * OUT_CH + lane], wB0 = Wh[(k + 0) * OUT_CH + c2];
    float wA1 = Wh[(k + 1) * OUT_CH + lane], wB1 = Wh[(k + 1) * OUT_CH + c2];
    float wA2 = Wh[(k + 2) * OUT_CH + lane], wB2 = Wh[(k + 2) * OUT_CH + c2];
    float wA3 = Wh[(k + 3) * OUT_CH + lane], wB3 = Wh[(k + 3) * OUT_CH + c2];
    a00 = fmaf(X0.x, wA0, a00); a01 = fmaf(X0.x, wB0, a01);
    a00 = fmaf(X0.y, wA1, a00); a01 = fmaf(X0.y, wB1, a01);
    a00 = fmaf(X0.z, wA2, a00); a01 = fmaf(X0.z, wB2, a01);
    a00 = fmaf(X0.w, wA3, a00); a01 = fmaf(X0.w, wB3, a01);
    a10 = fmaf(X1.x, wA0, a10); a11 = fmaf(X1.x, wB0, a11);
    a10 = fmaf(X1.y, wA1, a10); a11 = fmaf(X1.y, wB1, a11);
    a10 = fmaf(X1.z, wA2, a10); a11 = fmaf(X1.z, wB2, a11);
    a10 = fmaf(X1.w, wA3, a10); a11 = fmaf(X1.w, wB3, a11);
  }
  int gn0 = tile + n0;
  out[gn0 * OUT_CH + lane] = a00;
  out[(gn0 + 1) * OUT_CH + lane] = a10;
  if (lane < 48) {
    out[gn0 * OUT_CH + 64 + lane] = a01;
    out[(gn0 + 1) * OUT_CH + 64 + lane] = a11;
  }
}

extern "C" void kernel_launch(void* const* d_in, const int* in_sizes, int n_in,
                              void* d_out, int out_size, void* d_ws, size_t ws_size,
                              hipStream_t stream) {
  (void)in_sizes; (void)n_in; (void)out_size; (void)ws_size;
  const float* x    = (const float*)d_in[0];
  const int*   ei   = (const int*)d_in[1];
  const float* encW = (const float*)d_in[2];
  const float* encb = (const float*)d_in[3];
  const float* lng  = (const float*)d_in[4];
  const float* lnb  = (const float*)d_in[5];
  const float* tv   = (const float*)d_in[6];
  const float* W1   = (const float*)d_in[7];
  const float* b1   = (const float*)d_in[8];
  const float* mg   = (const float*)d_in[9];
  const float* mb   = (const float*)d_in[10];
  const float* W2   = (const float*)d_in[11];
  const float* b2   = (const float*)d_in[12];
  const float* Wh   = (const float*)d_in[13];
  const float* bh   = (const float*)d_in[14];

  char* ws = (char*)d_ws;
  int*   deg  = (int*)(ws + 0);            // N ints
  int*   cur  = (int*)(ws + 40000);        // N ints
  int*   offs = (int*)(ws + 80000);        // N+1 ints
  int*   csr  = (int*)(ws + 120064);       // E ints
  float* h    = (float*)(ws + 760064);     // N_PAD*64
  float* z0   = (float*)(ws + 3324160);    // N_PAD*64
  float* z1   = (float*)(ws + 5888256);    // N_PAD*64
  float* WP   = (float*)(ws + 8452352);    // 28*16384 (end 10,287,360)

  hipMemsetAsync(ws, 0, 80000, stream);    // deg + cur
  k_count<<<625, 256, 0, stream>>>(ei, deg);
  k_pack<<<28, 256, 0, stream>>>(W1, W2, WP);
  k_scan<<<1, 1024, 0, stream>>>(deg, offs);
  k_fill<<<625, 256, 0, stream>>>(ei, offs, cur, csr);
  k_encoder<<<1250, 256, 0, stream>>>(x, encW, encb, lng, lnb, h, z0);

  float* zc = z0;
  float* znx = z1;
  for (int l = 0; l < NLAYERS; l++) {
    int ln_next = (l + 1 < NLAYERS) ? (l + 1) : l;
    k_layer<<<500, 256, 0, stream>>>(zc, znx, h, offs, csr, tv, WP,
                                     b1, mg, mb, b2,
                                     lng + ln_next * H, lnb + ln_next * H,
                                     l, (l == NLAYERS - 1) ? 1 : 0);
    float* tmp = zc; zc = znx; znx = tmp;
  }
  k_head<<<1250, 256, 0, stream>>>(h, Wh, bh, (float*)d_out);
}